// Round 1
// baseline (768.318 us; speedup 1.0000x reference)
//
#include <hip/hip_runtime.h>

typedef unsigned short ushort_t;
typedef __attribute__((ext_vector_type(8))) short short8;   // 8 bf16 = 4 VGPRs (MFMA A/B frag)
typedef __attribute__((ext_vector_type(4))) float f32x4;    // MFMA C/D frag

#define NN 50000
#define EE 500000
#define DD 128
#define MAXT 10.0f

#define MFMA(a,b,c) __builtin_amdgcn_mfma_f32_16x16x32_bf16((a),(b),(c),0,0,0)

__device__ __forceinline__ ushort_t f2bf(float x){          // RNE float->bf16
  unsigned u = __float_as_uint(x);
  u += 0x7FFFu + ((u>>16)&1u);
  return (ushort_t)(u>>16);
}
__device__ __forceinline__ float sigm(float x){ return 1.0f/(1.0f+__expf(-x)); }
__device__ __forceinline__ float siluf(float x){ return x*sigm(x); }
__device__ __forceinline__ float clamp10(float x){ return fminf(fmaxf(x,-MAXT),MAXT); }

// load 8 consecutive fp32, convert to bf16x8 frag
__device__ __forceinline__ short8 ldcvt(const float* p){
  f32x4 x = *(const f32x4*)p;
  f32x4 y = *(const f32x4*)(p+4);
  short8 t;
  #pragma unroll
  for (int j=0;j<4;++j){ t[j]=(short)f2bf(x[j]); t[j+4]=(short)f2bf(y[j]); }
  return t;
}

// ---------------------------------------------------------------------------
// Weight prep: bf16, transposed to [n][k], XOR-swizzled rows, k sigma-permuted
// for mats fed by sigma-packed activations. sigma: stored pos kidx of natural
// col c is kidx = 8*(c&15) + (c>>4)  =>  c(kidx) = 16*(kidx&7) + (kidx>>3).
// mats: 0 W1a (We1 rows 0..127)   1 W1b (We1 rows 128..255)
//       2 W2(sigma)  3 Wc1(sigma) 4 Wn1a 5 Wn1b 6 Wn2(sigma)
// ---------------------------------------------------------------------------
__global__ void k_prep(const float* __restrict__ We1, const float* __restrict__ We2,
                       const float* __restrict__ Wc1, const float* __restrict__ Wn1,
                       const float* __restrict__ Wn2, ushort_t* __restrict__ wpre)
{
  int idx = blockIdx.x*256 + threadIdx.x;
  if (idx >= 7*16384) return;
  int mat = idx >> 14;
  int loc = idx & 16383;
  int n = loc >> 7;
  int kidx = loc & 127;
  int ko = 16*(kidx&7) + (kidx>>3);
  float v;
  switch(mat){
    case 0: v = We1[kidx*DD + n]; break;
    case 1: v = We1[(128+kidx)*DD + n]; break;
    case 2: v = We2[ko*DD + n]; break;
    case 3: v = Wc1[ko*DD + n]; break;
    case 4: v = Wn1[kidx*DD + n]; break;
    case 5: v = Wn1[(128+kidx)*DD + n]; break;
    default: v = Wn2[ko*DD + n]; break;
  }
  int byteoff = n*256 + ((kidx*2) ^ ((n&7)<<4));   // XOR swizzle (16B granule)
  *(ushort_t*)((char*)wpre + (size_t)mat*32768 + byteoff) = f2bf(v);
}

// ---------------------------------------------------------------------------
// CSR build
// ---------------------------------------------------------------------------
__global__ void k_zero(int* __restrict__ cnt){
  int i = blockIdx.x*256 + threadIdx.x;
  if (i < NN) cnt[i] = 0;
}
__global__ void k_count(const int* __restrict__ eidx, int* __restrict__ cnt){
  int e = blockIdx.x*256 + threadIdx.x;
  if (e < EE) atomicAdd(&cnt[eidx[e]], 1);
}
__global__ void k_scan(const int* __restrict__ cnt, int* __restrict__ rowstart,
                       int* __restrict__ cursor)
{
  __shared__ int part[1024];
  const int t = threadIdx.x;
  const int C = 49;                    // 1024*49 >= NN
  int c0 = t*C, c1 = min(c0+C, NN);
  int sum = 0;
  for (int i=c0;i<c1;++i) sum += cnt[i];
  part[t] = sum; __syncthreads();
  for (int off=1; off<1024; off<<=1){
    int v = (t>=off)? part[t-off] : 0;
    __syncthreads();
    part[t] += v;
    __syncthreads();
  }
  int run = (t>0)? part[t-1] : 0;
  for (int i=c0;i<c1;++i){ rowstart[i]=run; cursor[i]=run; run += cnt[i]; }
  if (t==0) rowstart[NN] = EE;
}
__global__ void k_scatter(const int* __restrict__ eidx, int* __restrict__ cursor,
                          int* __restrict__ csr){
  int e = blockIdx.x*256 + threadIdx.x;
  if (e < EE){
    int p = atomicAdd(&cursor[eidx[e]], 1);
    csr[p] = e;
  }
}

// ---------------------------------------------------------------------------
// Edge kernel: 128 edges/block, 4 waves M-split (32 edges/wave, full 128 cols)
// ---------------------------------------------------------------------------
__device__ __forceinline__ void gemm_lds(const ushort_t* ebuf, const ushort_t* Wbuf,
                                         int wv, int q, int s, f32x4 acc[2][8])
{
  #pragma unroll
  for (int kc=0;kc<4;++kc){
    const int koff = ((kc*64+q*16) ^ ((s&7)<<4));
    short8 a0 = *(const short8*)((const char*)ebuf + (wv*32+s)*256    + koff);
    short8 a1 = *(const short8*)((const char*)ebuf + (wv*32+16+s)*256 + koff);
    #pragma unroll
    for (int ct=0;ct<8;++ct){
      short8 bf = *(const short8*)((const char*)Wbuf + (ct*16+s)*256 + koff);
      acc[0][ct] = MFMA(a0,bf,acc[0][ct]);
      acc[1][ct] = MFMA(a1,bf,acc[1][ct]);
    }
  }
}
__device__ __forceinline__ void gemm_regA(const short8 af[2][4], const ushort_t* Wbuf,
                                          int q, int s, f32x4 acc[2][8])
{
  #pragma unroll
  for (int kc=0;kc<4;++kc){
    const int koff = ((kc*64+q*16) ^ ((s&7)<<4));
    #pragma unroll
    for (int ct=0;ct<8;++ct){
      short8 bf = *(const short8*)((const char*)Wbuf + (ct*16+s)*256 + koff);
      acc[0][ct] = MFMA(af[0][kc],bf,acc[0][ct]);
      acc[1][ct] = MFMA(af[1][kc],bf,acc[1][ct]);
    }
  }
}
__device__ __forceinline__ void zacc(f32x4 acc[2][8]){
  #pragma unroll
  for (int a=0;a<2;++a)
    #pragma unroll
    for (int b=0;b<8;++b) acc[a][b] = (f32x4){0.f,0.f,0.f,0.f};
}

__launch_bounds__(256,2)
__global__ void k_edge(const float* __restrict__ h,
                       const int* __restrict__ eidx,
                       const float* __restrict__ coord,
                       const float* __restrict__ We1,
                       const float* __restrict__ be1,
                       const float* __restrict__ be2,
                       const float* __restrict__ Watt,
                       const float* __restrict__ batt,
                       const float* __restrict__ bc1,
                       const float* __restrict__ Wc2,
                       const ushort_t* __restrict__ wpre,
                       float* __restrict__ ef_out,
                       float* __restrict__ trans)
{
  __shared__ ushort_t Wbuf[16384];   // 32KB weight tile [n][k] swizzled
  __shared__ ushort_t ebuf[16384];   // 32KB activation tile, sigma-packed
  const int tid = threadIdx.x;
  const int wv = tid>>6, ln = tid&63;
  const int q = ln>>4, s = ln&15;
  const int we0 = blockIdx.x*128 + wv*32;
  const int* rowI = eidx;
  const int* colI = eidx + EE;

  // per-lane edge geometry: lane holds edge we0+(ln&31) (lanes 32-63 duplicate)
  const int eM = min(we0 + (ln&31), EE-1);
  const int rM = rowI[eM], cM = colI[eM];
  const float cdx = coord[rM*3+0]-coord[cM*3+0];
  const float cdy = coord[rM*3+1]-coord[cM*3+1];
  const float cdz = coord[rM*3+2]-coord[cM*3+2];
  const float radial = cdx*cdx+cdy*cdy+cdz*cdz;

  // A-row node ids for the two 16-edge subtiles of this wave
  const int eS0 = min(we0 + s,      EE-1);
  const int eS1 = min(we0 + 16 + s, EE-1);
  const int nR0 = rowI[eS0], nR1 = rowI[eS1];
  const int nC0 = colI[eS0], nC1 = colI[eS1];

  f32x4 acc[2][8];
  zacc(acc);
  short8 af[2][4];

  // ---- GEMM1a: h[row] @ W1a -------------------------------------------------
  #pragma unroll
  for (int kc=0;kc<4;++kc){
    af[0][kc] = ldcvt(h + (size_t)nR0*DD + kc*32 + q*8);
    af[1][kc] = ldcvt(h + (size_t)nR1*DD + kc*32 + q*8);
  }
  { const f32x4* src=(const f32x4*)(wpre); f32x4* dst=(f32x4*)Wbuf;
    #pragma unroll
    for(int i=0;i<8;++i) dst[tid+256*i]=src[tid+256*i]; }
  __syncthreads();
  gemm_regA(af, Wbuf, q, s, acc);

  // ---- GEMM1b: h[col] @ W1b (accumulate) -----------------------------------
  #pragma unroll
  for (int kc=0;kc<4;++kc){
    af[0][kc] = ldcvt(h + (size_t)nC0*DD + kc*32 + q*8);
    af[1][kc] = ldcvt(h + (size_t)nC1*DD + kc*32 + q*8);
  }
  __syncthreads();
  { const f32x4* src=(const f32x4*)(wpre+16384); f32x4* dst=(f32x4*)Wbuf;
    #pragma unroll
    for(int i=0;i<8;++i) dst[tid+256*i]=src[tid+256*i]; }
  __syncthreads();
  gemm_regA(af, Wbuf, q, s, acc);

  // ---- e1 = silu(acc + radial*w1r + be1) -> sigma-pack into ebuf -----------
  {
    float wr[8], bb[8];
    #pragma unroll
    for (int t=0;t<8;++t){ wr[t]=We1[256*DD + 16*t+s]; bb[t]=be1[16*t+s]; }
    #pragma unroll
    for (int mt=0;mt<2;++mt)
      #pragma unroll
      for (int r=0;r<4;++r){
        int mloc = mt*16 + q*4 + r;
        float rad = __shfl(radial, mloc);
        short8 pk;
        #pragma unroll
        for (int t=0;t<8;++t){
          float v = siluf(acc[mt][t][r] + rad*wr[t] + bb[t]);
          pk[t]=(short)f2bf(v);
        }
        int m = wv*32 + mloc;
        *(short8*)((char*)ebuf + m*256 + ((s*16) ^ ((m&7)<<4))) = pk;
      }
  }
  zacc(acc);
  __syncthreads();
  { const f32x4* src=(const f32x4*)(wpre+2*16384); f32x4* dst=(f32x4*)Wbuf;
    #pragma unroll
    for(int i=0;i<8;++i) dst[tid+256*i]=src[tid+256*i]; }
  __syncthreads();

  // ---- GEMM2: ef_pre = silu(e1 @ W2 + be2); att; ef = ef_pre*att -----------
  gemm_lds(ebuf, Wbuf, wv, q, s, acc);
  {
    float wa[8], bb[8];
    #pragma unroll
    for (int t=0;t<8;++t){ wa[t]=Watt[16*t+s]; bb[t]=be2[16*t+s]; }
    const float bat = batt[0];
    #pragma unroll
    for (int mt=0;mt<2;++mt)
      #pragma unroll
      for (int r=0;r<4;++r){
        #pragma unroll
        for (int t=0;t<8;++t) acc[mt][t][r] = siluf(acc[mt][t][r] + bb[t]);
        float p=0.f;
        #pragma unroll
        for (int t=0;t<8;++t) p += acc[mt][t][r]*wa[t];
        p += __shfl_xor(p,1); p += __shfl_xor(p,2);
        p += __shfl_xor(p,4); p += __shfl_xor(p,8);
        const float att = sigm(p + bat);
        #pragma unroll
        for (int t=0;t<8;++t) acc[mt][t][r] *= att;
      }
    // write ef to global (fp32) and sigma-pack into ebuf (own rows only)
    #pragma unroll
    for (int mt=0;mt<2;++mt)
      #pragma unroll
      for (int r=0;r<4;++r){
        int mloc = mt*16+q*4+r;
        int e = we0 + mloc;
        short8 pk;
        #pragma unroll
        for (int t=0;t<8;++t){
          float v = acc[mt][t][r];
          pk[t]=(short)f2bf(v);
          if (e < EE) ef_out[(size_t)e*DD + 16*t+s] = v;
        }
        int m = wv*32+mloc;
        *(short8*)((char*)ebuf + m*256 + ((s*16) ^ ((m&7)<<4))) = pk;
      }
  }
  zacc(acc);
  __syncthreads();
  { const f32x4* src=(const f32x4*)(wpre+3*16384); f32x4* dst=(f32x4*)Wbuf;
    #pragma unroll
    for(int i=0;i<8;++i) dst[tid+256*i]=src[tid+256*i]; }
  __syncthreads();

  // ---- GEMM3: cw = silu(ef@Wc1+bc1)@Wc2 ; trans = clip(cdiff*cw) -----------
  gemm_lds(ebuf, Wbuf, wv, q, s, acc);
  {
    float wc[8], bb[8];
    #pragma unroll
    for (int t=0;t<8;++t){ wc[t]=Wc2[16*t+s]; bb[t]=bc1[16*t+s]; }
    #pragma unroll
    for (int mt=0;mt<2;++mt)
      #pragma unroll
      for (int r=0;r<4;++r){
        float p=0.f;
        #pragma unroll
        for (int t=0;t<8;++t) p += siluf(acc[mt][t][r]+bb[t])*wc[t];
        p += __shfl_xor(p,1); p += __shfl_xor(p,2);
        p += __shfl_xor(p,4); p += __shfl_xor(p,8);
        int mloc = mt*16+q*4+r;
        int e = we0+mloc;
        float dx = __shfl(cdx, mloc), dy = __shfl(cdy, mloc), dz = __shfl(cdz, mloc);
        if (e < EE && s == 0){
          trans[(size_t)e*3+0] = clamp10(dx*p);
          trans[(size_t)e*3+1] = clamp10(dy*p);
          trans[(size_t)e*3+2] = clamp10(dz*p);
        }
      }
  }
}

// ---------------------------------------------------------------------------
// Node aggregation (atomic-free via CSR): agg, coord_out
// ---------------------------------------------------------------------------
__launch_bounds__(256)
__global__ void k_agg(const float* __restrict__ ef,
                      const float* __restrict__ trans,
                      const int* __restrict__ rowstart,
                      const int* __restrict__ csr,
                      const float* __restrict__ coord,
                      float* __restrict__ agg,
                      float* __restrict__ coord_out)
{
  const int wv = threadIdx.x>>6, ln = threadIdx.x&63;
  const int n = blockIdx.x*4 + wv;
  if (n >= NN) return;
  const int rs = rowstart[n], re = rowstart[n+1];
  const int deg = re - rs;
  const int half = ln>>5, l4 = (ln&31)*4;
  float a0=0,a1=0,a2=0,a3=0;
  for (int j=half; j<deg; j+=2){
    const float* p = ef + (size_t)csr[rs+j]*DD + l4;
    f32x4 v = *(const f32x4*)p;
    a0+=v[0]; a1+=v[1]; a2+=v[2]; a3+=v[3];
  }
  a0 += __shfl_xor(a0,32); a1 += __shfl_xor(a1,32);
  a2 += __shfl_xor(a2,32); a3 += __shfl_xor(a3,32);
  if (half==0){
    f32x4 o = {a0,a1,a2,a3};
    *(f32x4*)(agg + (size_t)n*DD + l4) = o;
  }
  float tx=0,ty=0,tz=0;
  for (int j=ln;j<deg;j+=64){
    const float* t = trans + (size_t)csr[rs+j]*3;
    tx+=t[0]; ty+=t[1]; tz+=t[2];
  }
  #pragma unroll
  for (int m=1;m<64;m<<=1){
    tx+=__shfl_xor(tx,m); ty+=__shfl_xor(ty,m); tz+=__shfl_xor(tz,m);
  }
  if (ln==0){
    const float inv = 1.0f/(float)max(deg,1);
    coord_out[(size_t)n*3+0] = coord[(size_t)n*3+0] + clamp10(tx*inv);
    coord_out[(size_t)n*3+1] = coord[(size_t)n*3+1] + clamp10(ty*inv);
    coord_out[(size_t)n*3+2] = coord[(size_t)n*3+2] + clamp10(tz*inv);
  }
}

// ---------------------------------------------------------------------------
// Node MLP: h_out = h + silu([h,agg]@Wn1+bn1)@Wn2 + bn2
// ---------------------------------------------------------------------------
__launch_bounds__(256,2)
__global__ void k_node(const float* __restrict__ h,
                       const float* __restrict__ agg,
                       const ushort_t* __restrict__ wpre,
                       const float* __restrict__ bn1,
                       const float* __restrict__ bn2,
                       float* __restrict__ hout)
{
  __shared__ ushort_t Wbuf[16384];
  __shared__ ushort_t ubuf[16384];
  const int tid = threadIdx.x;
  const int wv = tid>>6, ln = tid&63;
  const int q = ln>>4, s = ln&15;
  const int n0 = blockIdx.x*128 + wv*32;
  const int nd0 = min(n0 + s,      NN-1);
  const int nd1 = min(n0 + 16 + s, NN-1);

  f32x4 acc[2][8];
  zacc(acc);
  short8 af[2][4];

  // pass 1: A = h
  #pragma unroll
  for (int kc=0;kc<4;++kc){
    af[0][kc] = ldcvt(h + (size_t)nd0*DD + kc*32 + q*8);
    af[1][kc] = ldcvt(h + (size_t)nd1*DD + kc*32 + q*8);
  }
  { const f32x4* src=(const f32x4*)(wpre+4*16384); f32x4* dst=(f32x4*)Wbuf;
    #pragma unroll
    for(int i=0;i<8;++i) dst[tid+256*i]=src[tid+256*i]; }
  __syncthreads();
  gemm_regA(af, Wbuf, q, s, acc);

  // pass 2: A = agg
  #pragma unroll
  for (int kc=0;kc<4;++kc){
    af[0][kc] = ldcvt(agg + (size_t)nd0*DD + kc*32 + q*8);
    af[1][kc] = ldcvt(agg + (size_t)nd1*DD + kc*32 + q*8);
  }
  __syncthreads();
  { const f32x4* src=(const f32x4*)(wpre+5*16384); f32x4* dst=(f32x4*)Wbuf;
    #pragma unroll
    for(int i=0;i<8;++i) dst[tid+256*i]=src[tid+256*i]; }
  __syncthreads();
  gemm_regA(af, Wbuf, q, s, acc);

  // u = silu(acc + bn1) -> sigma-pack
  {
    float bb[8];
    #pragma unroll
    for (int t=0;t<8;++t) bb[t]=bn1[16*t+s];
    #pragma unroll
    for (int mt=0;mt<2;++mt)
      #pragma unroll
      for (int r=0;r<4;++r){
        int mloc = mt*16+q*4+r;
        short8 pk;
        #pragma unroll
        for (int t=0;t<8;++t) pk[t]=(short)f2bf(siluf(acc[mt][t][r]+bb[t]));
        int m = wv*32+mloc;
        *(short8*)((char*)ubuf + m*256 + ((s*16) ^ ((m&7)<<4))) = pk;
      }
  }
  zacc(acc);
  __syncthreads();
  { const f32x4* src=(const f32x4*)(wpre+6*16384); f32x4* dst=(f32x4*)Wbuf;
    #pragma unroll
    for(int i=0;i<8;++i) dst[tid+256*i]=src[tid+256*i]; }
  __syncthreads();

  gemm_lds(ubuf, Wbuf, wv, q, s, acc);

  {
    float bb[8];
    #pragma unroll
    for (int t=0;t<8;++t) bb[t]=bn2[16*t+s];
    #pragma unroll
    for (int mt=0;mt<2;++mt)
      #pragma unroll
      for (int r=0;r<4;++r){
        int n = n0 + mt*16 + q*4 + r;
        if (n < NN){
          #pragma unroll
          for (int t=0;t<8;++t){
            int c = 16*t+s;
            hout[(size_t)n*DD+c] = h[(size_t)n*DD+c] + acc[mt][t][r] + bb[t];
          }
        }
      }
  }
}

// ---------------------------------------------------------------------------
extern "C" void kernel_launch(void* const* d_in, const int* in_sizes, int n_in,
                              void* d_out, int out_size, void* d_ws, size_t ws_size,
                              hipStream_t stream)
{
  const float* h    = (const float*)d_in[0];
  const int*   eidx = (const int*)  d_in[1];
  const float* coord= (const float*)d_in[2];
  const float* We1  = (const float*)d_in[3];
  const float* be1  = (const float*)d_in[4];
  const float* We2  = (const float*)d_in[5];
  const float* be2  = (const float*)d_in[6];
  const float* Watt = (const float*)d_in[7];
  const float* batt = (const float*)d_in[8];
  const float* Wc1  = (const float*)d_in[9];
  const float* bc1  = (const float*)d_in[10];
  const float* Wc2  = (const float*)d_in[11];
  const float* Wn1  = (const float*)d_in[12];
  const float* bn1  = (const float*)d_in[13];
  const float* Wn2  = (const float*)d_in[14];
  const float* bn2  = (const float*)d_in[15];

  float* hout     = (float*)d_out;
  float* coordout = hout + (size_t)NN*DD;              // +6,400,000
  float* efout    = coordout + (size_t)NN*3;           // +6,550,000

  char* ws = (char*)d_ws;
  float* trans   = (float*)(ws);                        // E*3 f32   = 6,000,000 B
  float* agg     = (float*)(ws + 6000000);              // N*128 f32 = 25,600,000 B
  int*   cnt     = (int*)  (ws + 31600000);             // N
  int*   cursor  = (int*)  (ws + 31800000);             // N
  int*   rowstart= (int*)  (ws + 32000000);             // N+1
  int*   csr     = (int*)  (ws + 32200064);             // E
  ushort_t* wpre = (ushort_t*)(ws + 34200064);          // 7*32768 B

  k_prep   <<<448, 256, 0, stream>>>(We1, We2, Wc1, Wn1, Wn2, wpre);
  k_zero   <<<196, 256, 0, stream>>>(cnt);
  k_count  <<<1954,256, 0, stream>>>(eidx, cnt);
  k_scan   <<<1,  1024, 0, stream>>>(cnt, rowstart, cursor);
  k_scatter<<<1954,256, 0, stream>>>(eidx, cursor, csr);
  k_edge   <<<3907,256, 0, stream>>>(h, eidx, coord, We1, be1, be2, Watt, batt,
                                     bc1, Wc2, wpre, efout, trans);
  k_agg    <<<12500,256,0, stream>>>(efout, trans, rowstart, csr, coord, agg, coordout);
  k_node   <<<391, 256, 0, stream>>>(h, agg, wpre, bn1, bn2, hout);
}

// Round 2
// 661.391 us; speedup vs baseline: 1.1617x; 1.1617x over previous
//
#include <hip/hip_runtime.h>

typedef unsigned short ushort_t;
typedef __attribute__((ext_vector_type(8))) short short8;   // 8 bf16 = 4 VGPRs (MFMA A/B frag)
typedef __attribute__((ext_vector_type(4))) float f32x4;    // MFMA C/D frag

#define NN 50000
#define EE 500000
#define DD 128
#define MAXT 10.0f

#define MFMA(a,b,c) __builtin_amdgcn_mfma_f32_16x16x32_bf16((a),(b),(c),0,0,0)

__device__ __forceinline__ ushort_t f2bf(float x){          // RNE float->bf16
  unsigned u = __float_as_uint(x);
  u += 0x7FFFu + ((u>>16)&1u);
  return (ushort_t)(u>>16);
}
__device__ __forceinline__ float sigm(float x){ return 1.0f/(1.0f+__expf(-x)); }
__device__ __forceinline__ float siluf(float x){ return x*sigm(x); }
__device__ __forceinline__ float clamp10(float x){ return fminf(fmaxf(x,-MAXT),MAXT); }

// load 8 consecutive fp32, convert to bf16x8 frag
__device__ __forceinline__ short8 ldcvt(const float* p){
  f32x4 x = *(const f32x4*)p;
  f32x4 y = *(const f32x4*)(p+4);
  short8 t;
  #pragma unroll
  for (int j=0;j<4;++j){ t[j]=(short)f2bf(x[j]); t[j+4]=(short)f2bf(y[j]); }
  return t;
}

// ---------------------------------------------------------------------------
// Weight prep: bf16, transposed to [n][k], XOR-swizzled rows, k sigma-permuted
// for mats fed by sigma-packed activations. sigma: stored pos kidx of natural
// col c is kidx = 8*(c&15) + (c>>4)  =>  c(kidx) = 16*(kidx&7) + (kidx>>3).
// mats: 0 W1a  1 W1b  2 W2(sigma)  3 Wc1(sigma)  4 Wn1a  5 Wn1b  6 Wn2(sigma)
// ---------------------------------------------------------------------------
__global__ void k_prep(const float* __restrict__ We1, const float* __restrict__ We2,
                       const float* __restrict__ Wc1, const float* __restrict__ Wn1,
                       const float* __restrict__ Wn2, ushort_t* __restrict__ wpre)
{
  int idx = blockIdx.x*256 + threadIdx.x;
  if (idx >= 7*16384) return;
  int mat = idx >> 14;
  int loc = idx & 16383;
  int n = loc >> 7;
  int kidx = loc & 127;
  int ko = 16*(kidx&7) + (kidx>>3);
  float v;
  switch(mat){
    case 0: v = We1[kidx*DD + n]; break;
    case 1: v = We1[(128+kidx)*DD + n]; break;
    case 2: v = We2[ko*DD + n]; break;
    case 3: v = Wc1[ko*DD + n]; break;
    case 4: v = Wn1[kidx*DD + n]; break;
    case 5: v = Wn1[(128+kidx)*DD + n]; break;
    default: v = Wn2[ko*DD + n]; break;
  }
  int byteoff = n*256 + ((kidx*2) ^ ((n&7)<<4));   // XOR swizzle (16B granule)
  *(ushort_t*)((char*)wpre + (size_t)mat*32768 + byteoff) = f2bf(v);
}

// ---------------------------------------------------------------------------
// CSR build (parallel scan; bsum/boff alias the csr buffer, overwritten later)
// ---------------------------------------------------------------------------
__global__ void k_zero(int* __restrict__ cnt){
  int i = blockIdx.x*256 + threadIdx.x;
  if (i < NN) cnt[i] = 0;
}
__global__ void k_count(const int* __restrict__ eidx, int* __restrict__ cnt){
  int e = blockIdx.x*256 + threadIdx.x;
  if (e < EE) atomicAdd(&cnt[eidx[e]], 1);
}
#define SCAN_B 196
__global__ void k_bsum(const int* __restrict__ cnt, int* __restrict__ bsum){
  __shared__ int sh[256];
  int t = threadIdx.x;
  int i = blockIdx.x*256 + t;
  sh[t] = (i < NN) ? cnt[i] : 0;
  __syncthreads();
  for (int off=128; off>0; off>>=1){
    if (t < off) sh[t] += sh[t+off];
    __syncthreads();
  }
  if (t==0) bsum[blockIdx.x] = sh[0];
}
__global__ void k_bscan(const int* __restrict__ bsum, int* __restrict__ boff){
  __shared__ int sh[256];
  int t = threadIdx.x;
  sh[t] = (t < SCAN_B) ? bsum[t] : 0;
  __syncthreads();
  for (int off=1; off<256; off<<=1){
    int x = (t>=off) ? sh[t-off] : 0;
    __syncthreads();
    sh[t] += x;
    __syncthreads();
  }
  if (t < SCAN_B) boff[t] = (t>0) ? sh[t-1] : 0;
}
__global__ void k_rscan(const int* __restrict__ cnt, const int* __restrict__ boff,
                        int* __restrict__ rowstart, int* __restrict__ cursor){
  __shared__ int sh[256];
  int t = threadIdx.x;
  int i = blockIdx.x*256 + t;
  int v = (i < NN) ? cnt[i] : 0;
  sh[t] = v;
  __syncthreads();
  for (int off=1; off<256; off<<=1){
    int x = (t>=off) ? sh[t-off] : 0;
    __syncthreads();
    sh[t] += x;
    __syncthreads();
  }
  int excl = sh[t] - v + boff[blockIdx.x];
  if (i < NN){ rowstart[i] = excl; cursor[i] = excl; }
  if (i == 0) rowstart[NN] = EE;
}
__global__ void k_scatter(const int* __restrict__ eidx, int* __restrict__ cursor,
                          int* __restrict__ csr){
  int e = blockIdx.x*256 + threadIdx.x;
  if (e < EE){
    int p = atomicAdd(&cursor[eidx[e]], 1);
    csr[p] = e;
  }
}

// ---------------------------------------------------------------------------
// Edge kernel: 128 edges/block, 8 waves, 16 edges/wave x full 128 cols
// ---------------------------------------------------------------------------
__device__ __forceinline__ void gemm_lds8(const ushort_t* ebuf, const ushort_t* Wbuf,
                                          int wv, int q, int s, f32x4 acc[8])
{
  #pragma unroll
  for (int kc=0;kc<4;++kc){
    const int koff = ((kc*64+q*16) ^ ((s&7)<<4));
    short8 a0 = *(const short8*)((const char*)ebuf + (wv*16+s)*256 + koff);
    #pragma unroll
    for (int ct=0;ct<8;++ct){
      short8 bf = *(const short8*)((const char*)Wbuf + (ct*16+s)*256 + koff);
      acc[ct] = MFMA(a0,bf,acc[ct]);
    }
  }
}
__device__ __forceinline__ void gemm_regA8(const short8 af[4], const ushort_t* Wbuf,
                                           int q, int s, f32x4 acc[8])
{
  #pragma unroll
  for (int kc=0;kc<4;++kc){
    const int koff = ((kc*64+q*16) ^ ((s&7)<<4));
    #pragma unroll
    for (int ct=0;ct<8;++ct){
      short8 bf = *(const short8*)((const char*)Wbuf + (ct*16+s)*256 + koff);
      acc[ct] = MFMA(af[kc],bf,acc[ct]);
    }
  }
}
__device__ __forceinline__ void zacc8(f32x4 acc[8]){
  #pragma unroll
  for (int b=0;b<8;++b) acc[b] = (f32x4){0.f,0.f,0.f,0.f};
}

__launch_bounds__(512,4)
__global__ void k_edge(const float* __restrict__ h,
                       const int* __restrict__ eidx,
                       const float* __restrict__ coord,
                       const float* __restrict__ We1,
                       const float* __restrict__ be1,
                       const float* __restrict__ be2,
                       const float* __restrict__ Watt,
                       const float* __restrict__ batt,
                       const float* __restrict__ bc1,
                       const float* __restrict__ Wc2,
                       const ushort_t* __restrict__ wpre,
                       float* __restrict__ ef_out,
                       float* __restrict__ trans)
{
  __shared__ ushort_t Wbuf[16384];   // 32KB weight tile [n][k] swizzled
  __shared__ ushort_t ebuf[16384];   // 32KB activation tile, sigma-packed
  const int tid = threadIdx.x;
  const int wv = tid>>6, ln = tid&63;
  const int q = ln>>4, s = ln&15;
  const int we0 = blockIdx.x*128 + wv*16;
  const int* rowI = eidx;
  const int* colI = eidx + EE;

  // per-lane edge geometry: lanes 0-15 hold this wave's 16 edges (rest dup)
  const int eM = min(we0 + (ln&15), EE-1);
  const int rM = rowI[eM], cM = colI[eM];
  const float cdx = coord[rM*3+0]-coord[cM*3+0];
  const float cdy = coord[rM*3+1]-coord[cM*3+1];
  const float cdz = coord[rM*3+2]-coord[cM*3+2];
  const float radial = cdx*cdx+cdy*cdy+cdz*cdz;

  // A-row node ids for this wave's 16-edge tile
  const int eS0 = min(we0 + s, EE-1);
  const int nR0 = rowI[eS0], nC0 = colI[eS0];

  f32x4 acc[8];
  zacc8(acc);
  short8 af[4];

  // ---- GEMM1a: h[row] @ W1a -------------------------------------------------
  #pragma unroll
  for (int kc=0;kc<4;++kc)
    af[kc] = ldcvt(h + (size_t)nR0*DD + kc*32 + q*8);
  { const f32x4* src=(const f32x4*)(wpre); f32x4* dst=(f32x4*)Wbuf;
    #pragma unroll
    for(int i=0;i<4;++i) dst[tid+512*i]=src[tid+512*i]; }
  __syncthreads();
  gemm_regA8(af, Wbuf, q, s, acc);

  // ---- GEMM1b: h[col] @ W1b (accumulate) -----------------------------------
  #pragma unroll
  for (int kc=0;kc<4;++kc)
    af[kc] = ldcvt(h + (size_t)nC0*DD + kc*32 + q*8);
  __syncthreads();
  { const f32x4* src=(const f32x4*)(wpre+16384); f32x4* dst=(f32x4*)Wbuf;
    #pragma unroll
    for(int i=0;i<4;++i) dst[tid+512*i]=src[tid+512*i]; }
  __syncthreads();
  gemm_regA8(af, Wbuf, q, s, acc);

  // ---- e1 = silu(acc + radial*w1r + be1) -> sigma-pack into ebuf -----------
  {
    float wr[8], bb[8];
    #pragma unroll
    for (int t=0;t<8;++t){ wr[t]=We1[256*DD + 16*t+s]; bb[t]=be1[16*t+s]; }
    #pragma unroll
    for (int r=0;r<4;++r){
      int mloc = q*4 + r;
      float rad = __shfl(radial, mloc);
      short8 pk;
      #pragma unroll
      for (int t=0;t<8;++t){
        float v = siluf(acc[t][r] + rad*wr[t] + bb[t]);
        pk[t]=(short)f2bf(v);
      }
      int m = wv*16 + mloc;
      *(short8*)((char*)ebuf + m*256 + ((s*16) ^ ((m&7)<<4))) = pk;
    }
  }
  zacc8(acc);
  __syncthreads();
  { const f32x4* src=(const f32x4*)(wpre+2*16384); f32x4* dst=(f32x4*)Wbuf;
    #pragma unroll
    for(int i=0;i<4;++i) dst[tid+512*i]=src[tid+512*i]; }
  __syncthreads();

  // ---- GEMM2: ef_pre = silu(e1 @ W2 + be2); att; ef = ef_pre*att -----------
  gemm_lds8(ebuf, Wbuf, wv, q, s, acc);
  {
    float wa[8], bb[8];
    #pragma unroll
    for (int t=0;t<8;++t){ wa[t]=Watt[16*t+s]; bb[t]=be2[16*t+s]; }
    const float bat = batt[0];
    #pragma unroll
    for (int r=0;r<4;++r){
      #pragma unroll
      for (int t=0;t<8;++t) acc[t][r] = siluf(acc[t][r] + bb[t]);
      float p=0.f;
      #pragma unroll
      for (int t=0;t<8;++t) p += acc[t][r]*wa[t];
      p += __shfl_xor(p,1); p += __shfl_xor(p,2);
      p += __shfl_xor(p,4); p += __shfl_xor(p,8);
      const float att = sigm(p + bat);
      #pragma unroll
      for (int t=0;t<8;++t) acc[t][r] *= att;
    }
    // write ef to global (fp32) and sigma-pack into ebuf (own rows only)
    #pragma unroll
    for (int r=0;r<4;++r){
      int mloc = q*4 + r;
      int e = we0 + mloc;
      short8 pk;
      #pragma unroll
      for (int t=0;t<8;++t) pk[t]=(short)f2bf(acc[t][r]);
      int m = wv*16 + mloc;
      *(short8*)((char*)ebuf + m*256 + ((s*16) ^ ((m&7)<<4))) = pk;
      if (e < EE){
        float* rp = ef_out + (size_t)e*DD + s;
        #pragma unroll
        for (int t=0;t<8;++t) rp[16*t] = acc[t][r];
      }
    }
  }
  zacc8(acc);
  __syncthreads();
  { const f32x4* src=(const f32x4*)(wpre+3*16384); f32x4* dst=(f32x4*)Wbuf;
    #pragma unroll
    for(int i=0;i<4;++i) dst[tid+512*i]=src[tid+512*i]; }
  __syncthreads();

  // ---- GEMM3: cw = silu(ef@Wc1+bc1)@Wc2 ; trans = clip(cdiff*cw) -----------
  gemm_lds8(ebuf, Wbuf, wv, q, s, acc);
  {
    float wc[8], bb[8];
    #pragma unroll
    for (int t=0;t<8;++t){ wc[t]=Wc2[16*t+s]; bb[t]=bc1[16*t+s]; }
    #pragma unroll
    for (int r=0;r<4;++r){
      float p=0.f;
      #pragma unroll
      for (int t=0;t<8;++t) p += siluf(acc[t][r]+bb[t])*wc[t];
      p += __shfl_xor(p,1); p += __shfl_xor(p,2);
      p += __shfl_xor(p,4); p += __shfl_xor(p,8);
      int mloc = q*4 + r;
      int e = we0 + mloc;
      float dx = __shfl(cdx, mloc), dy = __shfl(cdy, mloc), dz = __shfl(cdz, mloc);
      if (e < EE && s == 0){
        trans[(size_t)e*3+0] = clamp10(dx*p);
        trans[(size_t)e*3+1] = clamp10(dy*p);
        trans[(size_t)e*3+2] = clamp10(dz*p);
      }
    }
  }
}

// ---------------------------------------------------------------------------
// Node aggregation (atomic-free via CSR): agg, coord_out
// ---------------------------------------------------------------------------
__launch_bounds__(256)
__global__ void k_agg(const float* __restrict__ ef,
                      const float* __restrict__ trans,
                      const int* __restrict__ rowstart,
                      const int* __restrict__ csr,
                      const float* __restrict__ coord,
                      float* __restrict__ agg,
                      float* __restrict__ coord_out)
{
  const int wv = threadIdx.x>>6, ln = threadIdx.x&63;
  const int n = blockIdx.x*4 + wv;
  if (n >= NN) return;
  const int rs = rowstart[n], re = rowstart[n+1];
  const int deg = re - rs;
  const int half = ln>>5, l4 = (ln&31)*4;
  float a0=0,a1=0,a2=0,a3=0;
  for (int j=half; j<deg; j+=2){
    const float* p = ef + (size_t)csr[rs+j]*DD + l4;
    f32x4 v = *(const f32x4*)p;
    a0+=v[0]; a1+=v[1]; a2+=v[2]; a3+=v[3];
  }
  a0 += __shfl_xor(a0,32); a1 += __shfl_xor(a1,32);
  a2 += __shfl_xor(a2,32); a3 += __shfl_xor(a3,32);
  if (half==0){
    f32x4 o = {a0,a1,a2,a3};
    *(f32x4*)(agg + (size_t)n*DD + l4) = o;
  }
  float tx=0,ty=0,tz=0;
  for (int j=ln;j<deg;j+=64){
    const float* t = trans + (size_t)csr[rs+j]*3;
    tx+=t[0]; ty+=t[1]; tz+=t[2];
  }
  #pragma unroll
  for (int m=1;m<64;m<<=1){
    tx+=__shfl_xor(tx,m); ty+=__shfl_xor(ty,m); tz+=__shfl_xor(tz,m);
  }
  if (ln==0){
    const float inv = 1.0f/(float)max(deg,1);
    coord_out[(size_t)n*3+0] = coord[(size_t)n*3+0] + clamp10(tx*inv);
    coord_out[(size_t)n*3+1] = coord[(size_t)n*3+1] + clamp10(ty*inv);
    coord_out[(size_t)n*3+2] = coord[(size_t)n*3+2] + clamp10(tz*inv);
  }
}

// ---------------------------------------------------------------------------
// Node MLP: h_out = h + silu([h,agg]@Wn1+bn1)@Wn2 + bn2
// ---------------------------------------------------------------------------
__launch_bounds__(512,4)
__global__ void k_node(const float* __restrict__ h,
                       const float* __restrict__ agg,
                       const ushort_t* __restrict__ wpre,
                       const float* __restrict__ bn1,
                       const float* __restrict__ bn2,
                       float* __restrict__ hout)
{
  __shared__ ushort_t Wbuf[16384];
  __shared__ ushort_t ubuf[16384];
  const int tid = threadIdx.x;
  const int wv = tid>>6, ln = tid&63;
  const int q = ln>>4, s = ln&15;
  const int n0 = blockIdx.x*128 + wv*16;
  const int nd0 = min(n0 + s, NN-1);

  f32x4 acc[8];
  zacc8(acc);
  short8 af[4];

  // pass 1: A = h
  #pragma unroll
  for (int kc=0;kc<4;++kc)
    af[kc] = ldcvt(h + (size_t)nd0*DD + kc*32 + q*8);
  { const f32x4* src=(const f32x4*)(wpre+4*16384); f32x4* dst=(f32x4*)Wbuf;
    #pragma unroll
    for(int i=0;i<4;++i) dst[tid+512*i]=src[tid+512*i]; }
  __syncthreads();
  gemm_regA8(af, Wbuf, q, s, acc);

  // pass 2: A = agg
  #pragma unroll
  for (int kc=0;kc<4;++kc)
    af[kc] = ldcvt(agg + (size_t)nd0*DD + kc*32 + q*8);
  __syncthreads();
  { const f32x4* src=(const f32x4*)(wpre+5*16384); f32x4* dst=(f32x4*)Wbuf;
    #pragma unroll
    for(int i=0;i<4;++i) dst[tid+512*i]=src[tid+512*i]; }
  __syncthreads();
  gemm_regA8(af, Wbuf, q, s, acc);

  // u = silu(acc + bn1) -> sigma-pack
  {
    float bb[8];
    #pragma unroll
    for (int t=0;t<8;++t) bb[t]=bn1[16*t+s];
    #pragma unroll
    for (int r=0;r<4;++r){
      int mloc = q*4 + r;
      short8 pk;
      #pragma unroll
      for (int t=0;t<8;++t) pk[t]=(short)f2bf(siluf(acc[t][r]+bb[t]));
      int m = wv*16 + mloc;
      *(short8*)((char*)ubuf + m*256 + ((s*16) ^ ((m&7)<<4))) = pk;
    }
  }
  zacc8(acc);
  __syncthreads();
  { const f32x4* src=(const f32x4*)(wpre+6*16384); f32x4* dst=(f32x4*)Wbuf;
    #pragma unroll
    for(int i=0;i<4;++i) dst[tid+512*i]=src[tid+512*i]; }
  __syncthreads();

  gemm_lds8(ubuf, Wbuf, wv, q, s, acc);

  {
    float bb[8];
    #pragma unroll
    for (int t=0;t<8;++t) bb[t]=bn2[16*t+s];
    #pragma unroll
    for (int r=0;r<4;++r){
      int n = n0 + q*4 + r;
      if (n < NN){
        const float* hp = h + (size_t)n*DD + s;
        float* op = hout + (size_t)n*DD + s;
        #pragma unroll
        for (int t=0;t<8;++t) op[16*t] = hp[16*t] + acc[t][r] + bb[t];
      }
    }
  }
}

// ---------------------------------------------------------------------------
extern "C" void kernel_launch(void* const* d_in, const int* in_sizes, int n_in,
                              void* d_out, int out_size, void* d_ws, size_t ws_size,
                              hipStream_t stream)
{
  const float* h    = (const float*)d_in[0];
  const int*   eidx = (const int*)  d_in[1];
  const float* coord= (const float*)d_in[2];
  const float* We1  = (const float*)d_in[3];
  const float* be1  = (const float*)d_in[4];
  const float* We2  = (const float*)d_in[5];
  const float* be2  = (const float*)d_in[6];
  const float* Watt = (const float*)d_in[7];
  const float* batt = (const float*)d_in[8];
  const float* Wc1  = (const float*)d_in[9];
  const float* bc1  = (const float*)d_in[10];
  const float* Wc2  = (const float*)d_in[11];
  const float* Wn1  = (const float*)d_in[12];
  const float* bn1  = (const float*)d_in[13];
  const float* Wn2  = (const float*)d_in[14];
  const float* bn2  = (const float*)d_in[15];

  float* hout     = (float*)d_out;
  float* coordout = hout + (size_t)NN*DD;              // +6,400,000
  float* efout    = coordout + (size_t)NN*3;           // +6,550,000

  char* ws = (char*)d_ws;
  float* trans   = (float*)(ws);                        // E*3 f32   = 6,000,000 B
  float* agg     = (float*)(ws + 6000000);              // N*128 f32 = 25,600,000 B
  int*   cnt     = (int*)  (ws + 31600000);             // N
  int*   cursor  = (int*)  (ws + 31800000);             // N
  int*   rowstart= (int*)  (ws + 32000000);             // N+1
  int*   csr     = (int*)  (ws + 32200064);             // E
  ushort_t* wpre = (ushort_t*)(ws + 34200064);          // 7*32768 B
  // scan temporaries alias the csr buffer (overwritten later by k_scatter)
  int*   bsum    = csr;                                 // SCAN_B ints
  int*   boff    = csr + 256;                           // SCAN_B ints

  k_prep   <<<448, 256, 0, stream>>>(We1, We2, Wc1, Wn1, Wn2, wpre);
  k_zero   <<<196, 256, 0, stream>>>(cnt);
  k_count  <<<1954,256, 0, stream>>>(eidx, cnt);
  k_bsum   <<<196, 256, 0, stream>>>(cnt, bsum);
  k_bscan  <<<1,   256, 0, stream>>>(bsum, boff);
  k_rscan  <<<196, 256, 0, stream>>>(cnt, boff, rowstart, cursor);
  k_scatter<<<1954,256, 0, stream>>>(eidx, cursor, csr);
  k_edge   <<<3907,512, 0, stream>>>(h, eidx, coord, We1, be1, be2, Watt, batt,
                                     bc1, Wc2, wpre, efout, trans);
  k_agg    <<<12500,256,0, stream>>>(efout, trans, rowstart, csr, coord, agg, coordout);
  k_node   <<<391, 512, 0, stream>>>(h, agg, wpre, bn1, bn2, hout);
}